// Round 14
// baseline (223.745 us; speedup 1.0000x reference)
//
#include <hip/hip_runtime.h>

typedef __attribute__((ext_vector_type(8))) short short8b;   // 8 x bf16 (4 VGPRs)
typedef __attribute__((ext_vector_type(4))) float float4a;   // 4 x f32 acc

#define Lq   2048
#define NQf  (16*2048*64)     // elements per [16][2048][64] array
#define NROW (16*2048)

static __device__ inline unsigned short f2bf(float x){
    union{float f; unsigned u;} v; v.f = x;
    unsigned r = (v.u + 0x7fffu + ((v.u>>16)&1u))>>16;   // RNE
    return (unsigned short)r;
}
static __device__ inline float bf2f(unsigned short u){
    union{unsigned u; float f;} v; v.u = ((unsigned)u)<<16;
    return v.f;
}
// hardware RNE pack: lo16 = bf16(a), hi16 = bf16(b)
// NOTE: must be >= one barrier away from MFMA producers (R10/R11 NaN lesson)
static __device__ inline unsigned cvtpk(float a, float b){
    unsigned r;
    asm("v_cvt_pk_bf16_f32 %0, %1, %2" : "=v"(r) : "v"(a), "v"(b));
    return r;
}
union U8 { unsigned u[4]; short8b v8; };

// ---------------------------------------------------------------------------
// Single 2048-block launch. Blocks 0..1023: k1 body (LN+QKV+strided partials,
// bh=blk&15 -> XCD bh%8). Blocks 1024..2047: k2 body (window+merge+Wo+res,
// bh=(blk-1024)&15 -> same XCD as its producers). Per-bh counters gate k2.
// k1 blocks never wait (deadlock-free); k2 blocks enter as k1 retires.
// ---------------------------------------------------------------------------
__global__ __launch_bounds__(256, 4) void fused_all(
    const float* __restrict__ x,
    const float* __restrict__ Wq, const float* __restrict__ Wk,
    const float* __restrict__ Wv, const float* __restrict__ Wo,
    const float* __restrict__ lns, const float* __restrict__ lnb,
    unsigned short* __restrict__ Qb, unsigned short* __restrict__ Kb,
    unsigned short* __restrict__ Vb, unsigned short* __restrict__ ASb,
    float* __restrict__ MS, float* __restrict__ LS,
    float* __restrict__ out, unsigned* __restrict__ bar)
{
    __shared__ union {
        struct { unsigned short hl[32][72]; } a;                       // k1 LN
        struct { unsigned short Qg[32][72], Kg[32][72], Vg[32][72],
                                VgT[64][40], P[32][40]; } b;           // k1 tiles
        struct { unsigned short A[128][72];                            // k2
                 unsigned short VT[64][104];
                 unsigned short Pl[32][104];
                 float linv[32], esc[32]; } c;
    } u;

    const int tid = threadIdx.x;
    const int w = tid >> 6, lane = tid & 63;
    const int g = lane >> 4, c = lane & 15;

    if (blockIdx.x < 1024) {
        // ================= k1: LN + QKV + strided partials =================
        const int bh = blockIdx.x & 15, r = blockIdx.x >> 4;
        const int b_ = bh >> 3, h = bh & 7;
        const int Gbase = bh * Lq;

        short8b wfrag[3][2];
        #pragma unroll
        for (int q = 0; q < 3; ++q) {
            int pair = w*3 + q, p = pair >> 2, ne = pair & 3;
            const float* Wp = (p==0) ? Wq : (p==1) ? Wk : Wv;
            #pragma unroll
            for (int ks = 0; ks < 2; ++ks) {
                float f[8];
                #pragma unroll
                for (int uu = 0; uu < 8; ++uu)
                    f[uu] = Wp[(32*ks + 8*g + uu)*64 + 16*ne + c];
                U8 t;
                #pragma unroll
                for (int j = 0; j < 4; ++j) t.u[j] = cvtpk(f[2*j], f[2*j+1]);
                wfrag[q][ks] = t.v8;
            }
        }

        const float scl = lns[lane], bia = lnb[lane];
        #pragma unroll
        for (int t = 0; t < 8; ++t) {
            int s = w*8 + t;
            int n = (b_*2048 + r + 64*s)*8 + h;
            float xv = x[n*64 + lane];
            float s1 = xv, s2 = xv*xv;
            #pragma unroll
            for (int mk = 1; mk < 64; mk <<= 1) {
                s1 += __shfl_xor(s1, mk);
                s2 += __shfl_xor(s2, mk);
            }
            float mu  = s1 * (1.0f/64.0f);
            float var = s2 * (1.0f/64.0f) - mu*mu;
            float rs  = rsqrtf(var + 1e-5f);
            u.a.hl[s][lane] = f2bf((xv - mu)*rs*scl + bia);
        }
        __syncthreads();

        float4a accT[6];
        #pragma unroll
        for (int q = 0; q < 3; ++q) {
            #pragma unroll
            for (int mt = 0; mt < 2; ++mt) {
                float4a acc = {0.f,0.f,0.f,0.f};
                #pragma unroll
                for (int ks = 0; ks < 2; ++ks) {
                    short8b a = *(const short8b*)&u.a.hl[16*mt + c][32*ks + 8*g];
                    acc = __builtin_amdgcn_mfma_f32_16x16x32_bf16(a, wfrag[q][ks], acc, 0,0,0);
                }
                accT[q*2 + mt] = acc;
            }
        }
        __syncthreads();

        #pragma unroll
        for (int q = 0; q < 3; ++q) {
            int pair = w*3 + q, p = pair >> 2, ne = pair & 3;
            #pragma unroll
            for (int mt = 0; mt < 2; ++mt) {
                #pragma unroll
                for (int hf = 0; hf < 2; ++hf) {
                    int rr0 = 2*hf;
                    unsigned pkv = cvtpk(accT[q*2 + mt][rr0], accT[q*2 + mt][rr0+1]);
                    int tl0 = 16*mt + 4*g + rr0;
                    unsigned short lo = (unsigned short)(pkv & 0xffffu);
                    unsigned short hi = (unsigned short)(pkv >> 16);
                    if (p == 0)      { u.b.Qg[tl0][16*ne + c] = lo; u.b.Qg[tl0+1][16*ne + c] = hi; }
                    else if (p == 1) { u.b.Kg[tl0][16*ne + c] = lo; u.b.Kg[tl0+1][16*ne + c] = hi; }
                    else {
                        u.b.Vg[tl0][16*ne + c] = lo; u.b.Vg[tl0+1][16*ne + c] = hi;
                        *(unsigned*)&u.b.VgT[16*ne + c][tl0] = pkv;
                    }
                }
            }
        }
        __syncthreads();

        if (w < 2) {
            const int t_full = 16*w + c;
            float4a sa0 = {0.f,0.f,0.f,0.f}, sa1 = {0.f,0.f,0.f,0.f};
            #pragma unroll
            for (int ks = 0; ks < 2; ++ks) {
                short8b bq = *(const short8b*)&u.b.Qg[t_full][32*ks + 8*g];
                short8b a0 = *(const short8b*)&u.b.Kg[c     ][32*ks + 8*g];
                short8b a1 = *(const short8b*)&u.b.Kg[16 + c][32*ks + 8*g];
                sa0 = __builtin_amdgcn_mfma_f32_16x16x32_bf16(a0, bq, sa0, 0,0,0);
                sa1 = __builtin_amdgcn_mfma_f32_16x16x32_bf16(a1, bq, sa1, 0,0,0);
            }
            float pv[8];
            float m = -1e30f;
            #pragma unroll
            for (int st = 0; st < 2; ++st) {
                #pragma unroll
                for (int rr = 0; rr < 4; ++rr) {
                    int s_full = 16*st + 4*g + rr;
                    float s = (s_full == t_full) ? -1e30f
                              : ((st ? sa1[rr] : sa0[rr]) * 0.125f);
                    pv[4*st + rr] = s;
                    m = fmaxf(m, s);
                }
            }
            m = fmaxf(m, __shfl_xor(m, 16));
            m = fmaxf(m, __shfl_xor(m, 32));
            float lsum = 0.f;
            #pragma unroll
            for (int q = 0; q < 8; ++q) { pv[q] = __expf(pv[q] - m); lsum += pv[q]; }
            lsum += __shfl_xor(lsum, 16);
            lsum += __shfl_xor(lsum, 32);
            #pragma unroll
            for (int st = 0; st < 2; ++st) {
                uint2 pk;
                pk.x = cvtpk(pv[4*st+0], pv[4*st+1]);
                pk.y = cvtpk(pv[4*st+2], pv[4*st+3]);
                *(uint2*)&u.b.P[t_full][16*st + 4*g] = pk;
            }
            if (g == 0) {
                MS[Gbase + r + 64*t_full] = m;
                LS[Gbase + r + 64*t_full] = lsum;
            }
        } else {
            int i0 = tid - 128;
            #pragma unroll
            for (int i = 0; i < 6; ++i) {
                int uu = i0 + 128*i;             // 0..767
                int arr = uu >> 8, rem = uu & 255, tl = rem >> 3, cc = rem & 7;
                int goff = (Gbase + r + 64*tl)*64 + 8*cc;
                const unsigned short* src = (arr==0) ? &u.b.Qg[tl][0]
                                          : (arr==1) ? &u.b.Kg[tl][0] : &u.b.Vg[tl][0];
                unsigned short* dst = (arr==0) ? Qb : (arr==1) ? Kb : Vb;
                *(uint4*)&dst[goff] = *(const uint4*)&src[8*cc];
            }
        }
        __syncthreads();

        {
            const int mt = w & 1, nd0 = (w >> 1) * 2;
            short8b ap = *(const short8b*)&u.b.P[16*mt + c][8*g];
            short8b b0 = *(const short8b*)&u.b.VgT[16*nd0 + c][8*g];
            short8b b1 = *(const short8b*)&u.b.VgT[16*(nd0+1) + c][8*g];
            float4a z = {0.f,0.f,0.f,0.f};
            float4a o0 = __builtin_amdgcn_mfma_f32_16x16x32_bf16(ap, b0, z, 0,0,0);
            float4a o1 = __builtin_amdgcn_mfma_f32_16x16x32_bf16(ap, b1, z, 0,0,0);
            #pragma unroll
            for (int rr = 0; rr < 4; ++rr) {
                int t_full = 16*mt + 4*g + rr;
                int rowoff = (Gbase + r + 64*t_full)*64;
                ASb[rowoff + 16*nd0 + c]     = f2bf(o0[rr]);
                ASb[rowoff + 16*(nd0+1) + c] = f2bf(o1[rr]);
            }
        }

        // ---- signal: this bh-producer block is done (release) ----
        __threadfence();                     // each thread flushes its stores
        __syncthreads();                     // all fences before the atomic
        if (tid == 0) atomicAdd(&bar[bh*32], 1u);
    } else {
        // ================= k2: window + merge + Wo + residual ==============
        const int j2 = blockIdx.x - 1024;
        const int bh = j2 & 15, I = j2 >> 4;
        const int qbase = I * 32, j0 = qbase - 32;
        const int Gbase = bh * Lq;
        const int b_ = bh >> 3, hh = bh & 7;

        // ---- k1-independent prefetches (hide wait latency) ----
        short8b wofrag[2][2];
        #pragma unroll
        for (int ti2 = 0; ti2 < 2; ++ti2) {
            int ne = (w*2 + ti2) & 3;
            #pragma unroll
            for (int ks = 0; ks < 2; ++ks) {
                float f[8];
                #pragma unroll
                for (int uu = 0; uu < 8; ++uu)
                    f[uu] = Wo[(32*ks + 8*g + uu)*64 + 16*ne + c];
                U8 t;
                #pragma unroll
                for (int j = 0; j < 4; ++j) t.u[j] = cvtpk(f[2*j], f[2*j+1]);
                wofrag[ti2][ks] = t.v8;
            }
        }
        float xpre[2][4];
        #pragma unroll
        for (int ti2 = 0; ti2 < 2; ++ti2) {
            int tau = w*2 + ti2, mt = tau >> 2, ne = tau & 3;
            #pragma unroll
            for (int rr = 0; rr < 4; ++rr) {
                int tl = 16*mt + 4*g + rr;
                xpre[ti2][rr] = x[((b_*2048 + qbase + tl)*8 + hh)*64 + 16*ne + c];
            }
        }

        // ---- wait for this bh's 64 producers (acquire) ----
        if (tid == 0) {
            long spin = 0; unsigned cnt;
            do {
                cnt = __hip_atomic_load(&bar[bh*32], __ATOMIC_RELAXED,
                                        __HIP_MEMORY_SCOPE_AGENT);
                if (cnt >= 64u) break;
                __builtin_amdgcn_s_sleep(1);
            } while (++spin < (1L<<24));
        }
        __syncthreads();
        __threadfence();

        // ---- k1-dependent prefetches ----
        float msv = 0.f, lsv = 0.f;
        short8b qfrag[2] = {};
        if (w < 2) {
            int ti = 16*w + c;
            msv = MS[Gbase + qbase + ti];
            lsv = LS[Gbase + qbase + ti];
            #pragma unroll
            for (int ks = 0; ks < 2; ++ks)
                qfrag[ks] = *(const short8b*)&Qb[(Gbase + qbase + ti)*64 + 32*ks + 8*g];
        }
        uint4 aspre[2] = {};
        if (w >= 2) {
            int i0 = tid - 128;
            #pragma unroll
            for (int k = 0; k < 2; ++k) {
                int i = i0 + 128*k; int t = i >> 3, cc = i & 7;
                aspre[k] = *(const uint4*)&ASb[(Gbase + qbase + t)*64 + 8*cc];
            }
        }

        // ---- S0: stage K band (96 rows) ----
        #pragma unroll
        for (int i = 0; i < 3; ++i) {
            int uu = tid + 256*i;                  // 0..767
            int rr = uu >> 3, cc = uu & 7;
            int j = j0 + rr; j = j < 0 ? 0 : (j > 2047 ? 2047 : j);
            *(uint4*)&u.c.A[rr][8*cc] = *(const uint4*)&Kb[(Gbase + j)*64 + 8*cc];
        }
        __syncthreads();

        // ---- S1: score+softmax (waves 0,1) | VT build + ASl (waves 2,3) ----
        if (w < 2) {
            const int ti = 16*w + c;
            float4a acc[6];
            #pragma unroll
            for (int jt = 0; jt < 6; ++jt) acc[jt] = (float4a){0.f,0.f,0.f,0.f};
            #pragma unroll
            for (int ks = 0; ks < 2; ++ks) {
                #pragma unroll
                for (int jt = 0; jt < 6; ++jt) {
                    short8b ak = *(const short8b*)&u.c.A[16*jt + c][32*ks + 8*g];
                    acc[jt] = __builtin_amdgcn_mfma_f32_16x16x32_bf16(ak, qfrag[ks], acc[jt], 0,0,0);
                }
            }
            float pv[24];
            float m = -1e30f;
            #pragma unroll
            for (int jt = 0; jt < 6; ++jt) {
                #pragma unroll
                for (int rr = 0; rr < 4; ++rr) {
                    int jj = 16*jt + 4*g + rr;
                    int jv = j0 + jj;
                    bool valid = (jj > ti) && (jj < ti + 64) && (jv >= 0) && (jv < 2048);
                    float s = valid ? acc[jt][rr]*0.125f : -1e30f;
                    pv[4*jt + rr] = s;
                    m = fmaxf(m, s);
                }
            }
            m = fmaxf(m, __shfl_xor(m, 16));
            m = fmaxf(m, __shfl_xor(m, 32));
            m = fmaxf(m, msv);
            float lsum = 0.f;
            #pragma unroll
            for (int q = 0; q < 24; ++q) { pv[q] = __expf(pv[q] - m); lsum += pv[q]; }
            lsum += __shfl_xor(lsum, 16);
            lsum += __shfl_xor(lsum, 32);
            float es = __expf(msv - m);
            float l = lsum + lsv * es;
            #pragma unroll
            for (int jt = 0; jt < 6; ++jt) {
                uint2 pk;
                pk.x = cvtpk(pv[4*jt+0], pv[4*jt+1]);
                pk.y = cvtpk(pv[4*jt+2], pv[4*jt+3]);
                *(uint2*)&u.c.Pl[ti][16*jt + 4*g] = pk;
            }
            if (g == 0) { u.c.linv[ti] = 1.0f / l; u.c.esc[ti] = es; }
        } else {
            const int w2 = w - 2;
            #pragma unroll
            for (int q8 = 0; q8 < 6; ++q8) {
                unsigned short vv[8];
                #pragma unroll
                for (int q = 0; q < 8; ++q) {
                    int j = j0 + 48*w2 + 8*q8 + q;
                    j = j < 0 ? 0 : (j > 2047 ? 2047 : j);
                    vv[q] = Vb[(Gbase + j)*64 + lane];
                }
                uint4 pk;
                pk.x = vv[0] | ((unsigned)vv[1]<<16);
                pk.y = vv[2] | ((unsigned)vv[3]<<16);
                pk.z = vv[4] | ((unsigned)vv[5]<<16);
                pk.w = vv[6] | ((unsigned)vv[7]<<16);
                *(uint4*)&u.c.VT[lane][48*w2 + 8*q8] = pk;
            }
            int i0 = tid - 128;
            #pragma unroll
            for (int k = 0; k < 2; ++k) {
                int i = i0 + 128*k; int t = i >> 3, cc = i & 7;
                *(uint4*)&u.c.A[96+t][8*cc] = aspre[k];
            }
        }
        __syncthreads();

        // ---- S2: window PV (MFMA) + merge in-place (ASl -> Al) ----
        {
            const int mt = w & 1, nd0 = (w >> 1) * 2;
            float4a o0 = {0.f,0.f,0.f,0.f}, o1 = {0.f,0.f,0.f,0.f};
            #pragma unroll
            for (int ks = 0; ks < 3; ++ks) {
                short8b ap = *(const short8b*)&u.c.Pl[16*mt + c][32*ks + 8*g];
                short8b b0 = *(const short8b*)&u.c.VT[16*nd0 + c][32*ks + 8*g];
                short8b b1 = *(const short8b*)&u.c.VT[16*(nd0+1) + c][32*ks + 8*g];
                o0 = __builtin_amdgcn_mfma_f32_16x16x32_bf16(ap, b0, o0, 0,0,0);
                o1 = __builtin_amdgcn_mfma_f32_16x16x32_bf16(ap, b1, o1, 0,0,0);
            }
            #pragma unroll
            for (int rr = 0; rr < 4; ++rr) {
                int t = 16*mt + 4*g + rr;
                float li = u.c.linv[t], es = u.c.esc[t];
                float a0 = (o0[rr] + bf2f(u.c.A[96+t][16*nd0 + c]) * es) * li;
                float a1 = (o1[rr] + bf2f(u.c.A[96+t][16*(nd0+1) + c]) * es) * li;
                u.c.A[96+t][16*nd0 + c]     = f2bf(a0);
                u.c.A[96+t][16*(nd0+1) + c] = f2bf(a1);
            }
        }
        __syncthreads();

        // ---- S3: Wo projection (register B-fragments) + residual ----
        {
            #pragma unroll
            for (int ti2 = 0; ti2 < 2; ++ti2) {
                int tau = w*2 + ti2;                 // mt*4 + ne
                int mt = tau >> 2, ne = tau & 3;
                float4a acc = {0.f,0.f,0.f,0.f};
                #pragma unroll
                for (int ks = 0; ks < 2; ++ks) {
                    short8b a = *(const short8b*)&u.c.A[96 + 16*mt + c][32*ks + 8*g];
                    acc = __builtin_amdgcn_mfma_f32_16x16x32_bf16(a, wofrag[ti2][ks], acc, 0,0,0);
                }
                #pragma unroll
                for (int rr = 0; rr < 4; ++rr) {
                    int tl = 16*mt + 4*g + rr;
                    int idx = ((b_*2048 + qbase + tl)*8 + hh)*64 + 16*ne + c;
                    out[idx] = acc[rr] + xpre[ti2][rr];
                }
            }
        }
    }
}

// ---------------------------------------------------------------------------
extern "C" void kernel_launch(void* const* d_in, const int* in_sizes, int n_in,
                              void* d_out, int out_size, void* d_ws, size_t ws_size,
                              hipStream_t stream)
{
    const float* x   = (const float*)d_in[0];
    const float* Wq  = (const float*)d_in[1];
    const float* Wk  = (const float*)d_in[2];
    const float* Wv  = (const float*)d_in[3];
    const float* Wo  = (const float*)d_in[4];
    const float* lns = (const float*)d_in[5];
    const float* lnb = (const float*)d_in[6];
    float* out = (float*)d_out;

    unsigned short* Qb  = (unsigned short*)d_ws;
    unsigned short* Kb  = Qb + NQf;
    unsigned short* Vb  = Kb + NQf;
    unsigned short* ASb = Vb + NQf;
    float* MS = (float*)(ASb + NQf);
    float* LS = MS + NROW;
    unsigned* bar = (unsigned*)(LS + NROW);    // 16 counters, 128B apart

    hipMemsetAsync(bar, 0, 16*32*sizeof(unsigned), stream);
    fused_all<<<dim3(2048), dim3(256), 0, stream>>>(
        x, Wq, Wk, Wv, Wo, lns, lnb, Qb, Kb, Vb, ASb, MS, LS, out, bar);
}

// Round 15
// 29.105 us; speedup vs baseline: 7.6874x; 7.6874x over previous
//
#include <hip/hip_runtime.h>

typedef __attribute__((ext_vector_type(8))) short short8b;   // 8 x bf16 (4 VGPRs)
typedef __attribute__((ext_vector_type(4))) float float4a;   // 4 x f32 acc

#define Lq   2048
#define NQf  (16*2048*64)     // elements per [16][2048][64] array
#define NROW (16*2048)

static __device__ inline unsigned short f2bf(float x){
    union{float f; unsigned u;} v; v.f = x;
    unsigned r = (v.u + 0x7fffu + ((v.u>>16)&1u))>>16;   // RNE
    return (unsigned short)r;
}
static __device__ inline float bf2f(unsigned short u){
    union{unsigned u; float f;} v; v.u = ((unsigned)u)<<16;
    return v.f;
}
// hardware RNE pack: lo16 = bf16(a), hi16 = bf16(b)
// NOTE: must be >= one barrier away from MFMA producers (R10/R11 NaN lesson)
static __device__ inline unsigned cvtpk(float a, float b){
    unsigned r;
    asm("v_cvt_pk_bf16_f32 %0, %1, %2" : "=v"(r) : "v"(a), "v"(b));
    return r;
}
union U8 { unsigned u[4]; short8b v8; };

// ---------------------------------------------------------------------------
// Kernel 1: LN + QKV + strided partials (R12-proven body).
// XCD swizzle: bh = blockIdx & 15 -> XCD = bh % 8 under round-robin dispatch,
// so all 64 residue blocks of one bh share an XCD L2 with k2's consumers.
// ---------------------------------------------------------------------------
__global__ __launch_bounds__(256, 4) void k1_qkv_strided(
    const float* __restrict__ x,
    const float* __restrict__ Wq, const float* __restrict__ Wk,
    const float* __restrict__ Wv,
    const float* __restrict__ lns, const float* __restrict__ lnb,
    unsigned short* __restrict__ Qb, unsigned short* __restrict__ Kb,
    unsigned short* __restrict__ Vb, unsigned short* __restrict__ ASb,
    float* __restrict__ MS, float* __restrict__ LS)
{
    __shared__ union {
        struct { unsigned short hl[32][72]; } a;
        struct { unsigned short Qg[32][72], Kg[32][72], Vg[32][72],
                                VgT[64][40], P[32][40]; } b;   // 21504 B
    } u;

    const int tid = threadIdx.x;
    const int w = tid >> 6, lane = tid & 63;
    const int g = lane >> 4, c = lane & 15;
    const int bh = blockIdx.x & 15, r = blockIdx.x >> 4;   // XCD-aware decode
    const int b_ = bh >> 3, h = bh & 7;
    const int Gbase = bh * Lq;

    // ---- prefetch W B-fragments (block-invariant), cvt_pk packing ----
    short8b wfrag[3][2];
    #pragma unroll
    for (int q = 0; q < 3; ++q) {
        int pair = w*3 + q, p = pair >> 2, ne = pair & 3;
        const float* Wp = (p==0) ? Wq : (p==1) ? Wk : Wv;
        #pragma unroll
        for (int ks = 0; ks < 2; ++ks) {
            float f[8];
            #pragma unroll
            for (int uu = 0; uu < 8; ++uu)
                f[uu] = Wp[(32*ks + 8*g + uu)*64 + 16*ne + c];
            U8 t;
            #pragma unroll
            for (int j = 0; j < 4; ++j) t.u[j] = cvtpk(f[2*j], f[2*j+1]);
            wfrag[q][ks] = t.v8;
        }
    }

    // ---- LayerNorm -> hl ----
    const float scl = lns[lane], bia = lnb[lane];
    #pragma unroll
    for (int t = 0; t < 8; ++t) {
        int s = w*8 + t;
        int n = (b_*2048 + r + 64*s)*8 + h;
        float xv = x[n*64 + lane];
        float s1 = xv, s2 = xv*xv;
        #pragma unroll
        for (int mk = 1; mk < 64; mk <<= 1) {
            s1 += __shfl_xor(s1, mk);
            s2 += __shfl_xor(s2, mk);
        }
        float mu  = s1 * (1.0f/64.0f);
        float var = s2 * (1.0f/64.0f) - mu*mu;
        float rs  = rsqrtf(var + 1e-5f);
        u.a.hl[s][lane] = f2bf((xv - mu)*rs*scl + bia);
    }
    __syncthreads();

    // ---- QKV projection MFMAs (6 tiles/wave: 3 pairs x 2 mt) ----
    float4a accT[6];
    #pragma unroll
    for (int q = 0; q < 3; ++q) {
        #pragma unroll
        for (int mt = 0; mt < 2; ++mt) {
            float4a acc = {0.f,0.f,0.f,0.f};
            #pragma unroll
            for (int ks = 0; ks < 2; ++ks) {
                short8b a = *(const short8b*)&u.a.hl[16*mt + c][32*ks + 8*g];
                acc = __builtin_amdgcn_mfma_f32_16x16x32_bf16(a, wfrag[q][ks], acc, 0,0,0);
            }
            accT[q*2 + mt] = acc;
        }
    }
    __syncthreads();

    // ---- fragments -> LDS tiles (cvt_pk pairs along rr; post-barrier) ----
    #pragma unroll
    for (int q = 0; q < 3; ++q) {
        int pair = w*3 + q, p = pair >> 2, ne = pair & 3;
        #pragma unroll
        for (int mt = 0; mt < 2; ++mt) {
            #pragma unroll
            for (int hf = 0; hf < 2; ++hf) {
                int rr0 = 2*hf;
                unsigned pkv = cvtpk(accT[q*2 + mt][rr0], accT[q*2 + mt][rr0+1]);
                int tl0 = 16*mt + 4*g + rr0;
                unsigned short lo = (unsigned short)(pkv & 0xffffu);
                unsigned short hi = (unsigned short)(pkv >> 16);
                if (p == 0)      { u.b.Qg[tl0][16*ne + c] = lo; u.b.Qg[tl0+1][16*ne + c] = hi; }
                else if (p == 1) { u.b.Kg[tl0][16*ne + c] = lo; u.b.Kg[tl0+1][16*ne + c] = hi; }
                else {
                    u.b.Vg[tl0][16*ne + c] = lo; u.b.Vg[tl0+1][16*ne + c] = hi;
                    *(unsigned*)&u.b.VgT[16*ne + c][tl0] = pkv;
                }
            }
        }
    }
    __syncthreads();

    // ---- waves 0-1: strided scoring+softmax | waves 2-3: global Q/K/V writes
    if (w < 2) {
        const int t_full = 16*w + c;
        float4a sa0 = {0.f,0.f,0.f,0.f}, sa1 = {0.f,0.f,0.f,0.f};
        #pragma unroll
        for (int ks = 0; ks < 2; ++ks) {
            short8b bq = *(const short8b*)&u.b.Qg[t_full][32*ks + 8*g];
            short8b a0 = *(const short8b*)&u.b.Kg[c     ][32*ks + 8*g];
            short8b a1 = *(const short8b*)&u.b.Kg[16 + c][32*ks + 8*g];
            sa0 = __builtin_amdgcn_mfma_f32_16x16x32_bf16(a0, bq, sa0, 0,0,0);
            sa1 = __builtin_amdgcn_mfma_f32_16x16x32_bf16(a1, bq, sa1, 0,0,0);
        }
        float pv[8];
        float m = -1e30f;
        #pragma unroll
        for (int st = 0; st < 2; ++st) {
            #pragma unroll
            for (int rr = 0; rr < 4; ++rr) {
                int s_full = 16*st + 4*g + rr;
                float s = (s_full == t_full) ? -1e30f
                          : ((st ? sa1[rr] : sa0[rr]) * 0.125f);
                pv[4*st + rr] = s;
                m = fmaxf(m, s);
            }
        }
        m = fmaxf(m, __shfl_xor(m, 16));
        m = fmaxf(m, __shfl_xor(m, 32));
        float lsum = 0.f;
        #pragma unroll
        for (int q = 0; q < 8; ++q) { pv[q] = __expf(pv[q] - m); lsum += pv[q]; }
        lsum += __shfl_xor(lsum, 16);
        lsum += __shfl_xor(lsum, 32);
        #pragma unroll
        for (int st = 0; st < 2; ++st) {
            uint2 pk;
            pk.x = cvtpk(pv[4*st+0], pv[4*st+1]);
            pk.y = cvtpk(pv[4*st+2], pv[4*st+3]);
            *(uint2*)&u.b.P[t_full][16*st + 4*g] = pk;
        }
        if (g == 0) {
            MS[Gbase + r + 64*t_full] = m;
            LS[Gbase + r + 64*t_full] = lsum;
        }
    } else {
        int i0 = tid - 128;
        #pragma unroll
        for (int i = 0; i < 6; ++i) {
            int uu = i0 + 128*i;             // 0..767
            int arr = uu >> 8, rem = uu & 255, tl = rem >> 3, cc = rem & 7;
            int goff = (Gbase + r + 64*tl)*64 + 8*cc;
            const unsigned short* src = (arr==0) ? &u.b.Qg[tl][0]
                                      : (arr==1) ? &u.b.Kg[tl][0] : &u.b.Vg[tl][0];
            unsigned short* dst = (arr==0) ? Qb : (arr==1) ? Kb : Vb;
            *(uint4*)&dst[goff] = *(const uint4*)&src[8*cc];
        }
    }
    __syncthreads();

    // ---- strided PV (all waves) -> ASb ----
    {
        const int mt = w & 1, nd0 = (w >> 1) * 2;
        short8b ap = *(const short8b*)&u.b.P[16*mt + c][8*g];
        short8b b0 = *(const short8b*)&u.b.VgT[16*nd0 + c][8*g];
        short8b b1 = *(const short8b*)&u.b.VgT[16*(nd0+1) + c][8*g];
        float4a z = {0.f,0.f,0.f,0.f};
        float4a o0 = __builtin_amdgcn_mfma_f32_16x16x32_bf16(ap, b0, z, 0,0,0);
        float4a o1 = __builtin_amdgcn_mfma_f32_16x16x32_bf16(ap, b1, z, 0,0,0);
        #pragma unroll
        for (int rr = 0; rr < 4; ++rr) {
            int t_full = 16*mt + 4*g + rr;
            int rowoff = (Gbase + r + 64*t_full)*64;
            ASb[rowoff + 16*nd0 + c]     = f2bf(o0[rr]);
            ASb[rowoff + 16*(nd0+1) + c] = f2bf(o1[rr]);
        }
    }
}

// ---------------------------------------------------------------------------
// Kernel 2: window attention + merge + Wo + residual (R12-proven body).
// Same XCD-aware decode: consumers of bh land on the producers' XCD.
// ---------------------------------------------------------------------------
__global__ __launch_bounds__(256, 4) void k2_window_out(
    const float* __restrict__ x, const float* __restrict__ Wo,
    const unsigned short* __restrict__ Qb, const unsigned short* __restrict__ Kb,
    const unsigned short* __restrict__ Vb, const unsigned short* __restrict__ ASb,
    const float* __restrict__ MS, const float* __restrict__ LS,
    float* __restrict__ out)
{
    __shared__ struct {
        unsigned short A[128][72];   // rows0-95: K band; rows96-127: ASl -> Al
        unsigned short VT[64][104];  // window V^T tile [d][band-pos]
        unsigned short Pl[32][104];  // window P (bf16)
        float linv[32], esc[32];
    } sh;

    const int tid = threadIdx.x;
    const int w = tid >> 6, lane = tid & 63;
    const int g = lane >> 4, c = lane & 15;
    const int bh = blockIdx.x & 15, I = blockIdx.x >> 4;   // XCD-aware decode
    const int qbase = I * 32, j0 = qbase - 32;
    const int Gbase = bh * Lq;
    const int b_ = bh >> 3, hh = bh & 7;

    // ---------- top: register prefetches (latency hidden under S0) ---------
    short8b wofrag[2][2];                    // Wo B-fragments (block-invariant)
    #pragma unroll
    for (int ti2 = 0; ti2 < 2; ++ti2) {
        int ne = (w*2 + ti2) & 3;
        #pragma unroll
        for (int ks = 0; ks < 2; ++ks) {
            float f[8];
            #pragma unroll
            for (int uu = 0; uu < 8; ++uu)
                f[uu] = Wo[(32*ks + 8*g + uu)*64 + 16*ne + c];
            U8 t;
            #pragma unroll
            for (int j = 0; j < 4; ++j) t.u[j] = cvtpk(f[2*j], f[2*j+1]);
            wofrag[ti2][ks] = t.v8;
        }
    }
    float xpre[2][4];                        // residual values for final stores
    #pragma unroll
    for (int ti2 = 0; ti2 < 2; ++ti2) {
        int tau = w*2 + ti2, mt = tau >> 2, ne = tau & 3;
        #pragma unroll
        for (int rr = 0; rr < 4; ++rr) {
            int tl = 16*mt + 4*g + rr;
            xpre[ti2][rr] = x[((b_*2048 + qbase + tl)*8 + hh)*64 + 16*ne + c];
        }
    }
    float msv = 0.f, lsv = 0.f;
    short8b qfrag[2] = {};
    if (w < 2) {
        int ti = 16*w + c;
        msv = MS[Gbase + qbase + ti];
        lsv = LS[Gbase + qbase + ti];
        #pragma unroll
        for (int ks = 0; ks < 2; ++ks)
            qfrag[ks] = *(const short8b*)&Qb[(Gbase + qbase + ti)*64 + 32*ks + 8*g];
    }
    uint4 aspre[2] = {};
    if (w >= 2) {
        int i0 = tid - 128;
        #pragma unroll
        for (int k = 0; k < 2; ++k) {
            int i = i0 + 128*k; int t = i >> 3, cc = i & 7;
            aspre[k] = *(const uint4*)&ASb[(Gbase + qbase + t)*64 + 8*cc];
        }
    }

    // ---------- S0: stage K band (96 rows) ----------
    #pragma unroll
    for (int i = 0; i < 3; ++i) {
        int uu = tid + 256*i;                  // 0..767
        int rr = uu >> 3, cc = uu & 7;
        int j = j0 + rr; j = j < 0 ? 0 : (j > 2047 ? 2047 : j);
        *(uint4*)&sh.A[rr][8*cc] = *(const uint4*)&Kb[(Gbase + j)*64 + 8*cc];
    }
    __syncthreads();

    // ---------- S1: score+softmax (waves 0,1) | VT build + ASl (waves 2,3) --
    if (w < 2) {
        const int ti = 16*w + c;
        float4a acc[6];
        #pragma unroll
        for (int jt = 0; jt < 6; ++jt) acc[jt] = (float4a){0.f,0.f,0.f,0.f};
        #pragma unroll
        for (int ks = 0; ks < 2; ++ks) {
            #pragma unroll
            for (int jt = 0; jt < 6; ++jt) {
                short8b ak = *(const short8b*)&sh.A[16*jt + c][32*ks + 8*g];
                acc[jt] = __builtin_amdgcn_mfma_f32_16x16x32_bf16(ak, qfrag[ks], acc[jt], 0,0,0);
            }
        }
        float pv[24];
        float m = -1e30f;
        #pragma unroll
        for (int jt = 0; jt < 6; ++jt) {
            #pragma unroll
            for (int rr = 0; rr < 4; ++rr) {
                int jj = 16*jt + 4*g + rr;
                int jv = j0 + jj;
                bool valid = (jj > ti) && (jj < ti + 64) && (jv >= 0) && (jv < 2048);
                float s = valid ? acc[jt][rr]*0.125f : -1e30f;
                pv[4*jt + rr] = s;
                m = fmaxf(m, s);
            }
        }
        m = fmaxf(m, __shfl_xor(m, 16));
        m = fmaxf(m, __shfl_xor(m, 32));
        m = fmaxf(m, msv);
        float lsum = 0.f;
        #pragma unroll
        for (int q = 0; q < 24; ++q) { pv[q] = __expf(pv[q] - m); lsum += pv[q]; }
        lsum += __shfl_xor(lsum, 16);
        lsum += __shfl_xor(lsum, 32);
        float es = __expf(msv - m);
        float l = lsum + lsv * es;
        #pragma unroll
        for (int jt = 0; jt < 6; ++jt) {
            uint2 pk;
            pk.x = cvtpk(pv[4*jt+0], pv[4*jt+1]);
            pk.y = cvtpk(pv[4*jt+2], pv[4*jt+3]);
            *(uint2*)&sh.Pl[ti][16*jt + 4*g] = pk;
        }
        if (g == 0) { sh.linv[ti] = 1.0f / l; sh.esc[ti] = es; }
    } else {
        const int w2 = w - 2;
        #pragma unroll
        for (int q8 = 0; q8 < 6; ++q8) {
            unsigned short vv[8];
            #pragma unroll
            for (int q = 0; q < 8; ++q) {
                int j = j0 + 48*w2 + 8*q8 + q;
                j = j < 0 ? 0 : (j > 2047 ? 2047 : j);
                vv[q] = Vb[(Gbase + j)*64 + lane];
            }
            uint4 pk;
            pk.x = vv[0] | ((unsigned)vv[1]<<16);
            pk.y = vv[2] | ((unsigned)vv[3]<<16);
            pk.z = vv[4] | ((unsigned)vv[5]<<16);
            pk.w = vv[6] | ((unsigned)vv[7]<<16);
            *(uint4*)&sh.VT[lane][48*w2 + 8*q8] = pk;
        }
        int i0 = tid - 128;
        #pragma unroll
        for (int k = 0; k < 2; ++k) {
            int i = i0 + 128*k; int t = i >> 3, cc = i & 7;
            *(uint4*)&sh.A[96+t][8*cc] = aspre[k];     // ASl into freed rows
        }
    }
    __syncthreads();

    // ---------- S2: window PV (MFMA) + merge in-place (ASl -> Al) ----------
    {
        const int mt = w & 1, nd0 = (w >> 1) * 2;
        float4a o0 = {0.f,0.f,0.f,0.f}, o1 = {0.f,0.f,0.f,0.f};
        #pragma unroll
        for (int ks = 0; ks < 3; ++ks) {
            short8b ap = *(const short8b*)&sh.Pl[16*mt + c][32*ks + 8*g];
            short8b b0 = *(const short8b*)&sh.VT[16*nd0 + c][32*ks + 8*g];
            short8b b1 = *(const short8b*)&sh.VT[16*(nd0+1) + c][32*ks + 8*g];
            o0 = __builtin_amdgcn_mfma_f32_16x16x32_bf16(ap, b0, o0, 0,0,0);
            o1 = __builtin_amdgcn_mfma_f32_16x16x32_bf16(ap, b1, o1, 0,0,0);
        }
        #pragma unroll
        for (int rr = 0; rr < 4; ++rr) {
            int t = 16*mt + 4*g + rr;
            float li = sh.linv[t], es = sh.esc[t];
            // same thread reads then writes the same (t,col) — race-free
            float a0 = (o0[rr] + bf2f(sh.A[96+t][16*nd0 + c]) * es) * li;
            float a1 = (o1[rr] + bf2f(sh.A[96+t][16*(nd0+1) + c]) * es) * li;
            sh.A[96+t][16*nd0 + c]     = f2bf(a0);
            sh.A[96+t][16*(nd0+1) + c] = f2bf(a1);
        }
    }
    __syncthreads();

    // ---------- S3: Wo projection (register B-fragments) + residual --------
    {
        #pragma unroll
        for (int ti2 = 0; ti2 < 2; ++ti2) {
            int tau = w*2 + ti2;                 // mt*4 + ne
            int mt = tau >> 2, ne = tau & 3;
            float4a acc = {0.f,0.f,0.f,0.f};
            #pragma unroll
            for (int ks = 0; ks < 2; ++ks) {
                short8b a = *(const short8b*)&sh.A[96 + 16*mt + c][32*ks + 8*g];
                acc = __builtin_amdgcn_mfma_f32_16x16x32_bf16(a, wofrag[ti2][ks], acc, 0,0,0);
            }
            #pragma unroll
            for (int rr = 0; rr < 4; ++rr) {
                int tl = 16*mt + 4*g + rr;
                int idx = ((b_*2048 + qbase + tl)*8 + hh)*64 + 16*ne + c;
                out[idx] = acc[rr] + xpre[ti2][rr];
            }
        }
    }
}

// ---------------------------------------------------------------------------
extern "C" void kernel_launch(void* const* d_in, const int* in_sizes, int n_in,
                              void* d_out, int out_size, void* d_ws, size_t ws_size,
                              hipStream_t stream)
{
    const float* x   = (const float*)d_in[0];
    const float* Wq  = (const float*)d_in[1];
    const float* Wk  = (const float*)d_in[2];
    const float* Wv  = (const float*)d_in[3];
    const float* Wo  = (const float*)d_in[4];
    const float* lns = (const float*)d_in[5];
    const float* lnb = (const float*)d_in[6];
    float* out = (float*)d_out;

    unsigned short* Qb  = (unsigned short*)d_ws;
    unsigned short* Kb  = Qb + NQf;
    unsigned short* Vb  = Kb + NQf;
    unsigned short* ASb = Vb + NQf;
    float* MS = (float*)(ASb + NQf);
    float* LS = MS + NROW;

    k1_qkv_strided<<<dim3(1024), dim3(256), 0, stream>>>(
        x, Wq, Wk, Wv, lns, lnb, Qb, Kb, Vb, ASb, MS, LS);
    k2_window_out <<<dim3(1024), dim3(256), 0, stream>>>(
        x, Wo, Qb, Kb, Vb, ASb, MS, LS, out);
}